// Round 1
// 157.709 us; speedup vs baseline: 1.0117x; 1.0117x over previous
//
#include <hip/hip_runtime.h>

// HMM forward, LINEAR domain with power-of-2 rescaling. B=64 chains, D=128
// steps, A=128 states.
//   p_{t+1}[j] = (sum_k w[k] * E[t][k][j]) * eBC[b][t][j] * f_t
// E[t][j][k] = exp(u[t][k][j] - Z[t][k]) fp16, k-pairs (2i,2i+1).
// eBC = exp(bernoulli log-prob) = sigmoid(+-l), stored fp32 by prep.
// f_t = 2^-e, e = floor(log2 max_k w[k]) -- computed READER-side from the
// loaded fp16 values via a v_pk_max_f16 tree + v_permlane32_swap_b32, so it
// is identical in every lane/wave: stored values are uniformly scaled and no
// cross-wave max exchange (old vmaxl) is needed. Exponents accumulate in an
// int (Eacc); final L = Phi0 + ln2*Eacc + log(sum_j w).
// This removes from the per-step critical chain: ds_bpermute (shfl_xor),
// __logf, __expf, the writer-side DPP max chain + readlane, and the vmaxl
// LDS round trip. Remaining chain: barrier -> ds_read ew -> dot2 chain ->
// permlane32_swap -> mul -> cvt -> ds_write_b16 -> barrier.
// fwd: 64 blocks x 4 waves; wave w owns j in [32w,32w+32); lanes split k in
// halves. RAW s_barrier with lgkmcnt-only drain (global prefetch loads stay
// in flight). E prefetched 2 steps ahead into a 3-buffer VGPR rotation;
// sched_barrier(0) pins ds_reads first, then prefetch, then ALU.

#define B_ 64
#define D_ 128
#define A_ 128
#define T_ 127

// ws layout (4-byte units), ~8.32 MB
#define E16_UINTS (T_ * 8192)      // [t][q][h][w][jl][c] uints
#define BC_OFF E16_UINTS           // [b][t][j] fp32 = exp(bern log-prob)
#define BC_SZ (B_ * T_ * A_)
#define LP_OFF (BC_OFF + BC_SZ)    // log_p_a1[j] fp32

typedef _Float16 h2 __attribute__((ext_vector_type(2)));

__device__ __forceinline__ int packrtz(float a, float b) {
    auto p = __builtin_amdgcn_cvt_pkrtz(a, b); // low=a, high=b
    return __builtin_bit_cast(int, p);
}
__device__ __forceinline__ float dot2acc(unsigned int e, unsigned int s, float acc) {
    return __builtin_amdgcn_fdot2(__builtin_bit_cast(h2, e),
                                  __builtin_bit_cast(h2, s), acc, false);
}
__device__ __forceinline__ unsigned pkmax(unsigned a, unsigned b) {
    unsigned d;
    asm("v_pk_max_f16 %0, %1, %2" : "=v"(d) : "v"(a), "v"(b));
    return d;
}
__device__ __forceinline__ unsigned pkmax4(uint4 u) {
    return pkmax(pkmax(u.x, u.y), pkmax(u.z, u.w));
}

template <int CTRL>
__device__ __forceinline__ float dpp_mov_self(float x) {
    return __int_as_float(__builtin_amdgcn_update_dpp(
        __float_as_int(x), __float_as_int(x), CTRL, 0xF, 0xF, false));
}
template <int CTRL>
__device__ __forceinline__ float dpp_mov_zero(float x) {
    return __int_as_float(__builtin_amdgcn_update_dpp(
        0, __float_as_int(x), CTRL, 0xF, 0xF, true));
}
__device__ __forceinline__ float wave_max_bcast(float x) {
    x = fmaxf(x, dpp_mov_self<0x111>(x));
    x = fmaxf(x, dpp_mov_self<0x112>(x));
    x = fmaxf(x, dpp_mov_self<0x114>(x));
    x = fmaxf(x, dpp_mov_self<0x118>(x));
    x = fmaxf(x, dpp_mov_self<0x142>(x));
    x = fmaxf(x, dpp_mov_self<0x143>(x));
    return __int_as_float(__builtin_amdgcn_readlane(__float_as_int(x), 63));
}
__device__ __forceinline__ float wave_sum_bcast(float x) {
    x += dpp_mov_zero<0x111>(x);
    x += dpp_mov_zero<0x112>(x);
    x += dpp_mov_zero<0x114>(x);
    x += dpp_mov_zero<0x118>(x);
    x += dpp_mov_zero<0x142>(x);
    x += dpp_mov_zero<0x143>(x);
    return __int_as_float(__builtin_amdgcn_readlane(__float_as_int(x), 63));
}

// ---------------- single merged prep kernel: 127 blocks x 256 ----------------
__global__ __launch_bounds__(256) void prep(const float* __restrict__ uT,
                                            const float* __restrict__ u1,
                                            const float* __restrict__ x,
                                            const float* __restrict__ lg,
                                            float* __restrict__ ws,
                                            float* __restrict__ out) {
    __shared__ float Zl[A_];
    const int t = blockIdx.x, tid = threadIdx.x;
    const int wave = tid >> 6, lane = tid & 63;
    const float* u = uT + (size_t)t * A_ * A_;

    // Z[k] = lse_j u[k][j], wave-parallel per row
    for (int rr = 0; rr < 32; rr++) {
        int r = wave * 32 + rr;
        float a = u[r * A_ + lane];
        float c = u[r * A_ + lane + 64];
        float mx = wave_max_bcast(fmaxf(a, c));
        float s = wave_sum_bcast(__expf(a - mx) + __expf(c - mx));
        if (lane == 0) Zl[r] = mx + __logf(s);
    }
    __syncthreads();

    // E16 store, coalesced in the fwd-consumption layout:
    // addr_u(t,q,h,w,jl,c) = t*8192 + q*1024 + h*512 + w*128 + jl*4 + c
    // uint = pack(e(2i,j), e(2i+1,j)), i = 32h+4q+c, j = 32w+jl
    unsigned int* Et = (unsigned int*)ws + (size_t)t * 8192;
    for (int it = 0; it < 32; it++) {
        int a = it * 256 + tid;     // 0..8191
        int c = a & 3, jl = (a >> 2) & 31, w = (a >> 7) & 3;
        int h = (a >> 9) & 1, q = (a >> 10) & 7;
        int j = 32 * w + jl;
        int i = 32 * h + 4 * q + c;
        float e0 = __expf(u[(2 * i) * A_ + j] - Zl[2 * i]);
        float e1 = __expf(u[(2 * i + 1) * A_ + j] - Zl[2 * i + 1]);
        Et[a] = (unsigned int)packrtz(e0, e1);
    }

    // eBC[b][t][j] = exp(bern(x[b][t+1], j)) = sigmoid(+-l)
    {
        int j = tid & 127, hb = tid >> 7;
        float lv = lg[(t + 1) * A_ + j];
        float sg = 1.f / (1.f + __expf(-lv));   // P(x=1)
        float g1 = sg, g0 = 1.f - sg;           // P(x=0)
        float* BC = ws + BC_OFF;
        for (int b = hb * 32; b < hb * 32 + 32; b++) {
            float xv = x[b * D_ + t + 1];
            BC[((size_t)b * T_ + t) * A_ + j] = (xv != 0.f) ? g1 : g0;
        }
    }

    // block 0, wave 0: log_softmax(u1) -> LP + output 1
    if (t == 0 && wave == 0) {
        float a = u1[lane], c = u1[lane + 64];
        float mx = wave_max_bcast(fmaxf(a, c));
        float s = wave_sum_bcast(__expf(a - mx) + __expf(c - mx));
        float lse = mx + __logf(s);
        ws[LP_OFF + lane] = a - lse;
        ws[LP_OFF + lane + 64] = c - lse;
        out[B_ * A_ + lane] = a - lse;
        out[B_ * A_ + lane + 64] = c - lse;
    }
}

// ---------------- main: 64 blocks x 256 (4 waves), raw barriers ----------------
// RAW barrier: lgkmcnt drain only (LDS visibility); vmcnt loads stay in flight.
#define BARRIER() asm volatile("s_waitcnt lgkmcnt(0)\n\ts_barrier" ::: "memory")

#define STEP(T, EC, EP, BCC, BCP, DOPF)                                       \
    {                                                                         \
        const int p = (T) & 1, np = p ^ 1;                                    \
        const uint4* ewp = (const uint4*)&ewl[p][0] + h * 8;                  \
        uint4 ew_[8];                                                         \
        _Pragma("unroll") for (int q = 0; q < 8; q++) ew_[q] = ewp[q];        \
        __builtin_amdgcn_sched_barrier(0); /* ds_reads issue first */         \
        if (DOPF) { /* prefetch step T+2 into free buffer EP */               \
            const uint4* pf = (const uint4*)(Eb + (size_t)((T) + 2) * 32768); \
            _Pragma("unroll") for (int q = 0; q < 8; q++) EP[q] = pf[q * 256];\
            BCP = BCg[((T) + 2) * A_];                                        \
            __builtin_amdgcn_sched_barrier(0); /* pin loads here (no sink) */ \
        }                                                                     \
        /* reader-side max of loaded w (fp16) -> power-of-2 rescale f */      \
        unsigned mA = pkmax(pkmax(pkmax4(ew_[0]), pkmax4(ew_[1])),            \
                            pkmax(pkmax4(ew_[2]), pkmax4(ew_[3])));           \
        unsigned mB = pkmax(pkmax(pkmax4(ew_[4]), pkmax4(ew_[5])),            \
                            pkmax(pkmax4(ew_[6]), pkmax4(ew_[7])));           \
        unsigned mm = pkmax(mA, mB);                                          \
        auto mr = __builtin_amdgcn_permlane32_swap(mm, mm, false, false);     \
        mm = pkmax(mr[0], mr[1]);                                             \
        mm = pkmax(mm, mm >> 16);                                             \
        unsigned e16 = (mm >> 10) & 31;                                       \
        float f = __uint_as_float((142u - e16) << 23); /* 2^(15-e16) */       \
        Eacc += (int)e16 - 15;                                                \
        float bf = (BCC) * f;                                                 \
        float s0 = 0, s1 = 0, s2 = 0, s3 = 0;                                 \
        float r0 = 0, r1 = 0, r2 = 0, r3 = 0;                                 \
        _Pragma("unroll") for (int q = 0; q < 4; q++) {                       \
            s0 = dot2acc(EC[q].x, ew_[q].x, s0);                              \
            s1 = dot2acc(EC[q].y, ew_[q].y, s1);                              \
            s2 = dot2acc(EC[q].z, ew_[q].z, s2);                              \
            s3 = dot2acc(EC[q].w, ew_[q].w, s3);                              \
        }                                                                     \
        _Pragma("unroll") for (int q = 4; q < 8; q++) {                       \
            r0 = dot2acc(EC[q].x, ew_[q].x, r0);                              \
            r1 = dot2acc(EC[q].y, ew_[q].y, r1);                              \
            r2 = dot2acc(EC[q].z, ew_[q].z, r2);                              \
            r3 = dot2acc(EC[q].w, ew_[q].w, r3);                              \
        }                                                                     \
        float Sh = ((s0 + s1) + (s2 + s3)) + ((r0 + r1) + (r2 + r3));         \
        auto sr = __builtin_amdgcn_permlane32_swap(__float_as_uint(Sh),       \
                                                   __float_as_uint(Sh),       \
                                                   false, false);             \
        float Stot = __uint_as_float(sr[0]) + __uint_as_float(sr[1]);         \
        float pv = Stot * bf;                                                 \
        v = pv;                                                               \
        ewl[np][j] = (_Float16)pv;                                            \
        BARRIER();                                                            \
    }

__global__ __launch_bounds__(256, 1) void fwd(const float* __restrict__ x,
                                              const float* __restrict__ lg,
                                              const float* __restrict__ ws,
                                              float* __restrict__ out) {
    __shared__ __align__(16) _Float16 ewl[2][A_];
    __shared__ float sums[4];
    const int b = blockIdx.x, tid = threadIdx.x;
    const int w = tid >> 6, lane = tid & 63;
    const int h = lane >> 5, jl = lane & 31;
    const int j = 32 * w + jl;

    const char* Eb = (const char*)ws + (size_t)h * 2048 + w * 512 + jl * 16;
    const float* BCg = ws + BC_OFF + (size_t)b * T_ * A_ + j; // + t*A_
    const float* LP = ws + LP_OFF;

    // init v_0[j] = log_p_a1[j] + bern(x[b][0], j)  (log domain, once)
    float ll = lg[j];
    float sp = (ll > 0.f) ? (ll + log1pf(__expf(-ll))) : log1pf(__expf(ll));
    float xv0 = x[b * D_];
    float vlog = LP[j] + ((xv0 != 0.f) ? (ll - sp) : (-sp));
    float mw = wave_max_bcast(vlog);
    sums[w] = mw;
    BARRIER();
    float Phi0 = fmaxf(fmaxf(sums[0], sums[1]), fmaxf(sums[2], sums[3]));
    float v = __expf(vlog - Phi0);          // global max -> uniform scale
    ewl[0][j] = (_Float16)v;
    int Eacc = 0;

    uint4 E0[8], E1[8], E2[8];
    float bc0, bc1, bc2;
    {   // preload t=0 -> E0, t=1 -> E1 (E2 filled by step 0's prefetch)
        const uint4* p0 = (const uint4*)(Eb);
        const uint4* p1 = (const uint4*)(Eb + 32768);
#pragma unroll
        for (int q = 0; q < 8; q++) { E0[q] = p0[q * 256]; E1[q] = p1[q * 256]; }
        bc0 = BCg[0];
        bc1 = BCg[A_];
        __builtin_amdgcn_sched_barrier(0);
    }
    bc2 = 0.f;
    BARRIER();

    for (int t = 0; t < 123; t += 3) {  // steps 0..122
        STEP(t + 0, E0, E2, bc0, bc2, 1)
        STEP(t + 1, E1, E0, bc1, bc0, 1)
        STEP(t + 2, E2, E1, bc2, bc1, 1)
    }
    STEP(123, E0, E2, bc0, bc2, 1)  // pf 125 -> E2
    STEP(124, E1, E0, bc1, bc0, 1)  // pf 126 -> E0
    STEP(125, E2, E1, bc2, bc1, 0)
    STEP(126, E0, E1, bc0, bc1, 0)

    // final: L = Phi0 + ln2*Eacc + log(sum_j w_127[j])
    float sw = wave_sum_bcast(v) * 0.5f; // halves duplicate j
    sums[w] = sw;
    BARRIER();
    float tot = (sums[0] + sums[1]) + (sums[2] + sums[3]);
    float L = Phi0 + 0.69314718056f * (float)Eacc + __logf(tot);
    if (tid < A_) out[b * A_ + tid] = L;
}

extern "C" void kernel_launch(void* const* d_in, const int* in_sizes, int n_in,
                              void* d_out, int out_size, void* d_ws, size_t ws_size,
                              hipStream_t stream) {
    const float* x = (const float*)d_in[0];    // [B,D]
    const float* u1 = (const float*)d_in[1];   // [1,1,1,A]
    const float* uT = (const float*)d_in[2];   // [D-1,A,A]
    const float* lg = (const float*)d_in[3];   // [1,D,1,A]
    float* ws = (float*)d_ws;                  // ~8.32 MB
    float* out = (float*)d_out;

    prep<<<dim3(T_), dim3(256), 0, stream>>>(uT, u1, x, lg, ws, out);
    fwd<<<dim3(B_), dim3(256), 0, stream>>>(x, lg, ws, out);
}